// Round 6
// baseline (268.329 us; speedup 1.0000x reference)
//
#include <hip/hip_runtime.h>

#define B_    2048
#define K_    32
#define D_    768
#define DICT_ 24576
#define C_    64

#define CCHUNK   512                 // dict columns per bucket / tile block
#define DCHUNK   16                  // d rows per tile block
#define NCC      (DICT_ / CCHUNK)    // 48 buckets / col-chunks
#define NDC      (D_ / DCHUNK)       // 48 d-chunks
#define BCAP     2048                // per-bucket capacity (~20x expected ~102)
#define NITEMS   (B_ * K_)           // 65536

// workspace layout (in floats/ints):
//   [REC_F, +NCC*BCAP*4)  recs: int4 {item, di, w_bits, tgt} per bucket
//   [BDC_F, +DICT_)       bdc
//   [CNT_F, +NCC*16)      bucket counters, one per 64B line (memsetAsync-zeroed)
//   [ACC_F, +NITEMS)      pair-contribution accumulator (zeroed by scan)
#define REC_F 0
#define BDC_F (NCC * BCAP * 4)
#define CNT_F (BDC_F + DICT_)
#define ACC_F (CNT_F + NCC * 16)
#define WS_FLOATS (ACC_F + NITEMS)

// K_A: fused scan + bdc. Scan is latency-bound (2.3% HBM, 24.7% VALU, r4);
// bdc is pure-BW (75.5 MB stream). Disjoint resources -> run them in the SAME
// kernel so the stream hides under the scan's latency. 3 of every 32 waves
// (evenly spread through dispatch order) each compute 4 bdc rows:
// 65536/32*3 = 6144 quads * 4 = 24576 rows exactly.
__global__ void fused_scan_bdc(const float* __restrict__ up_vals,
                               const float* __restrict__ up_enc,
                               const float* __restrict__ b_dec,
                               const int*   __restrict__ up_idx,
                               const int*   __restrict__ down_idx,
                               const int*   __restrict__ conn,
                               int*   __restrict__ cnt,
                               int4*  __restrict__ recs,
                               float* __restrict__ bdc,
                               float* __restrict__ acc) {
    int wave = threadIdx.x >> 6;
    int lane = threadIdx.x & 63;
    int item = blockIdx.x * 4 + wave;      // item = b*32 + i (= global wave id)
    int b    = item >> 5;

    // ---- scan: emit pairs into 48 column-chunk buckets ----
    int di = down_idx[item];
    int allowed = conn[(size_t)di * C_ + lane];   // lane c holds slot c (C_==64)
    bool valid = allowed >= 0;
    int   myup  = up_idx[b * K_ + (lane & 31)];
    float myval = up_vals[b * K_ + (lane & 31)];

    if (lane == 0) acc[item] = 0.f;        // pair accumulator starts at 0

    unsigned jm = 0u;
    #pragma unroll
    for (int j = 0; j < K_; ++j) {
        int tgt = __builtin_amdgcn_readlane(myup, j);
        jm |= (valid && (allowed == tgt)) ? (1u << j) : 0u;
    }

    if (__ballot(jm != 0u)) {              // wave-uniform; ~7% of items
        #pragma unroll 1
        for (int j = 0; j < K_; ++j) {
            unsigned long long m = __ballot((jm >> j) & 1u);
            if (m != 0) {                  // wave-uniform
                int   t = __shfl(myup, j);
                float w = (float)__popcll(m) * __shfl(myval, j);
                if (lane == 0) {
                    int bi  = t >> 9;      // t / CCHUNK
                    int pos = atomicAdd(cnt + bi * 16, 1);   // 48 spread counters
                    if (pos < BCAP)
                        recs[bi * BCAP + pos] = make_int4(item, di, __float_as_int(w), t);
                }
            }
        }
    }

    // ---- bdc: rows [4q, 4q+4), q = (g>>5)*3 + (g&31) for g%32 < 3 ----
    if ((item & 31) < 3) {
        int quad = (item >> 5) * 3 + (item & 31);     // 0..6143
        const float4* bp = (const float4*)b_dec;
        #pragma unroll
        for (int rr = 0; rr < 4; ++rr) {
            int row = quad * 4 + rr;
            const float4* rp = (const float4*)(up_enc + (size_t)row * D_);
            float a2 = 0.f;
            #pragma unroll
            for (int i = 0; i < 3; ++i) {
                float4 a  = rp[lane + 64 * i];
                float4 bb = bp[lane + 64 * i];
                a2 += a.x * bb.x + a.y * bb.y + a.z * bb.z + a.w * bb.w;
            }
            #pragma unroll
            for (int off = 32; off; off >>= 1) a2 += __shfl_xor(a2, off);
            if (lane == 0) bdc[row] = a2;
        }
    }
}

// K_B: grid (cc, dc). Block streams a [16 x 512] tile of up_dec into LDS
// (one full pass over up_dec = 75.5 MB), reads ONLY its own bucket (~102
// records, coalesced), 16 MACs/pair vs LDS, atomicAdd into acc (NOT out:
// decoupling from the bias write removes the scan->bdc ordering).
__global__ __launch_bounds__(256) void pair_dot_kernel(const float* __restrict__ A,
                                                       const float* __restrict__ down_enc,
                                                       const int*  __restrict__ cnt,
                                                       const int4* __restrict__ recs,
                                                       float* __restrict__ acc) {
    __shared__ float tile[DCHUNK * CCHUNK];   // 32 KB
    int tid = threadIdx.x;
    int cc = blockIdx.x, dc = blockIdx.y;
    int c0 = cc * CCHUNK, d0 = dc * DCHUNK;

    int n = cnt[cc * 16];
    if (n > BCAP) n = BCAP;
    if (n == 0) return;

    #pragma unroll
    for (int k = 0; k < 8; ++k) {             // 16 rows x 128 float4 = 2048 f4
        int l  = tid + 256 * k;
        int r  = l >> 7, fi = l & 127;
        ((float4*)tile)[l] = *(const float4*)(A + (size_t)(d0 + r) * DICT_ + c0 + 4 * fi);
    }
    __syncthreads();

    const int4* bucket = recs + (size_t)cc * BCAP;
    for (int i = tid; i < n; i += 256) {
        int4 rec = bucket[i];                 // {item, di, w_bits, tgt}
        int t = rec.w - c0;
        const float4* dp = (const float4*)(down_enc + (size_t)rec.y * D_ + d0);
        float a2 = 0.f;
        #pragma unroll
        for (int q = 0; q < 4; ++q) {         // 16 d's
            float4 dv = dp[q];
            a2 += dv.x * tile[(4 * q + 0) * CCHUNK + t]
                + dv.y * tile[(4 * q + 1) * CCHUNK + t]
                + dv.z * tile[(4 * q + 2) * CCHUNK + t]
                + dv.w * tile[(4 * q + 3) * CCHUNK + t];
        }
        atomicAdd(acc + rec.x, __int_as_float(rec.z) * a2);
    }
}

// K_C: out[item] = bdc[up_idx[item]] + acc[item]. Coalesced; ~0.8 MB; ~2 us.
__global__ void merge_kernel(const float* __restrict__ bdc,
                             const float* __restrict__ acc,
                             const int*   __restrict__ up_idx,
                             float* __restrict__ out) {
    int i = blockIdx.x * 256 + threadIdx.x;
    out[i] = bdc[up_idx[i]] + acc[i];
}

// Fallback (no workspace): self-contained, column dots + inline bias.
__global__ void main_fallback(const float* __restrict__ up_vals,
                              const float* __restrict__ up_dec,
                              const float* __restrict__ down_enc,
                              const float* __restrict__ up_enc,
                              const float* __restrict__ b_dec,
                              const int*   __restrict__ up_idx,
                              const int*   __restrict__ down_idx,
                              const int*   __restrict__ conn,
                              float* __restrict__ out) {
    int wave = threadIdx.x >> 6;
    int lane = threadIdx.x & 63;
    int item = blockIdx.x * 4 + wave;
    int b    = item >> 5;

    int di = down_idx[item];
    int allowed = conn[(size_t)di * C_ + lane];
    bool valid = allowed >= 0;
    int   myup  = up_idx[b * K_ + (lane & 31)];
    float myval = up_vals[b * K_ + (lane & 31)];

    unsigned jm = 0u;
    #pragma unroll
    for (int j = 0; j < K_; ++j) {
        int tgt = __builtin_amdgcn_readlane(myup, j);
        jm |= (valid && (allowed == tgt)) ? (1u << j) : 0u;
    }

    float acc = 0.f;
    if (__ballot(jm != 0u)) {
        const float* drow = down_enc + (size_t)di * D_;
        #pragma unroll 1
        for (int j = 0; j < K_; ++j) {
            unsigned long long m = __ballot((jm >> j) & 1u);
            if (m != 0) {
                float w   = (float)__popcll(m) * __shfl(myval, j);
                int   tgt = __shfl(myup, j);
                const float* colp = up_dec + tgt;
                float partial = 0.f;
                #pragma unroll
                for (int ii = 0; ii < 12; ++ii) {
                    int d = lane + 64 * ii;
                    partial += drow[d] * colp[(size_t)d * DICT_];
                }
                acc += w * partial;
            }
        }
    }

    {   // inline bias
        int ui = up_idx[item];
        const float4* rp = (const float4*)(up_enc + (size_t)ui * D_);
        const float4* bp = (const float4*)b_dec;
        #pragma unroll
        for (int ii = 0; ii < 3; ++ii) {
            float4 a  = rp[lane + 64 * ii];
            float4 bb = bp[lane + 64 * ii];
            acc += a.x * bb.x + a.y * bb.y + a.z * bb.z + a.w * bb.w;
        }
    }

    #pragma unroll
    for (int off = 32; off; off >>= 1) acc += __shfl_xor(acc, off);
    if (lane == 0) out[item] = acc;
}

extern "C" void kernel_launch(void* const* d_in, const int* in_sizes, int n_in,
                              void* d_out, int out_size, void* d_ws, size_t ws_size,
                              hipStream_t stream) {
    (void)in_sizes; (void)n_in; (void)out_size;
    const float* up_vals  = (const float*)d_in[0];
    const float* up_dec   = (const float*)d_in[1];
    const float* down_enc = (const float*)d_in[2];
    const float* up_enc   = (const float*)d_in[3];
    const float* b_dec    = (const float*)d_in[4];
    const int*   up_idx   = (const int*)d_in[5];
    const int*   down_idx = (const int*)d_in[6];
    const int*   conn     = (const int*)d_in[7];
    float* out = (float*)d_out;

    if (ws_size < (size_t)WS_FLOATS * sizeof(float)) {
        main_fallback<<<(B_ * K_) / 4, 256, 0, stream>>>(up_vals, up_dec, down_enc,
                                                         up_enc, b_dec, up_idx,
                                                         down_idx, conn, out);
        return;
    }

    float* ws   = (float*)d_ws;
    int4*  recs = (int4*)(ws + REC_F);
    float* bdc  = ws + BDC_F;
    int*   cnt  = (int*)(ws + CNT_F);
    float* acc  = ws + ACC_F;

    hipMemsetAsync(cnt, 0, (size_t)NCC * 16 * sizeof(int), stream);
    fused_scan_bdc<<<NITEMS / 4, 256, 0, stream>>>(up_vals, up_enc, b_dec, up_idx,
                                                   down_idx, conn, cnt, recs, bdc, acc);
    pair_dot_kernel<<<dim3(NCC, NDC), 256, 0, stream>>>(up_dec, down_enc, cnt,
                                                        recs, acc);
    merge_kernel<<<NITEMS / 256, 256, 0, stream>>>(bdc, acc, up_idx, out);
}